// Round 1
// 459.205 us; speedup vs baseline: 1.1665x; 1.1665x over previous
//
#include <hip/hip_runtime.h>
#include <hip/hip_bf16.h>

#define N_NODES 100000
#define D_IN 128
#define D_H 256
#define D_E 64
#define MT 32        // nodes per GEMM block
#define SCAN_B 1024  // scan block size

typedef __attribute__((ext_vector_type(8))) short short8;
typedef __attribute__((ext_vector_type(4))) float floatx4;

__device__ inline unsigned short f2bf(float f) {
    union { float f; unsigned u; } v; v.f = f;
    unsigned r = v.u + 0x7FFF + ((v.u >> 16) & 1);
    return (unsigned short)(r >> 16);
}
__device__ inline unsigned f2bf2(float a, float b) {
    return (unsigned)f2bf(a) | ((unsigned)f2bf(b) << 16);
}
__device__ inline float2 bf2f2(unsigned v) {
    union { unsigned u; float f; } lo, hi;
    lo.u = v << 16;
    hi.u = v & 0xffff0000u;
    return make_float2(lo.f, hi.f);  // .x = lower-address bf16
}

#define MFMA16(a, b, c) __builtin_amdgcn_mfma_f32_16x16x32_bf16((a), (b), (c), 0, 0, 0)

// ---------------- weight pre-pack to bf16, SWIZZLED to MFMA fragment order ----
// B-fragment for (out-group g16=out>>4, ks, lane{quad,col}) is stored contiguously:
//   chunk_index = (g16*KS + ks)*64 + quad*16 + col   (chunk = 8 shorts = 16B)
//   element e of chunk = W[out = g16*16+col][k = ks*32 + quad*8 + e]
// -> every wave B-load is a fully coalesced 1KB global_load_dwordx4.
__global__ void convert_weights(const float* __restrict__ Wl1, const float* __restrict__ Wr1,
                                const float* __restrict__ Wl2, const float* __restrict__ Wr2,
                                const float* __restrict__ fc1W, const float* __restrict__ fc2W,
                                unsigned short* __restrict__ W1s, unsigned short* __restrict__ W2s,
                                unsigned short* __restrict__ F1s, unsigned short* __restrict__ F2s) {
    int idx = blockIdx.x * blockDim.x + threadIdx.x;
    if (idx < 65536) {
        // W1: 256 outs x 256 k of [Wl1 | Wr1]
        int out = idx >> 8, k = idx & 255;
        float v = (k < 128) ? Wl1[out * 128 + k] : Wr1[out * 128 + (k - 128)];
        int ks = k >> 5, quad = (k >> 3) & 3, e = k & 7, col = out & 15;
        int g = (out >> 4) * 8 + ks;
        W1s[(g * 64 + quad * 16 + col) * 8 + e] = f2bf(v);
    } else if (idx < 98304) {
        // W2: 128 outs x 256 k of [Wl2 ; Wr2]
        int i = idx - 65536; int out = i >> 8, k = i & 255;
        float v = (out < 64) ? Wl2[out * 256 + k] : Wr2[(out - 64) * 256 + k];
        int ks = k >> 5, quad = (k >> 3) & 3, e = k & 7, col = out & 15;
        int g = (out >> 4) * 8 + ks;
        W2s[(g * 64 + quad * 16 + col) * 8 + e] = f2bf(v);
    } else if (idx < 114688) {
        // fc1: 256 outs x 64 k
        int i = idx - 98304;
        int out = i >> 6, k = i & 63;
        float v = fc1W[i];
        int ks = k >> 5, quad = (k >> 3) & 3, e = k & 7, col = out & 15;
        int g = (out >> 4) * 2 + ks;
        F1s[(g * 64 + quad * 16 + col) * 8 + e] = f2bf(v);
    } else if (idx < 147456) {
        // fc2: 128 outs x 256 k
        int i = idx - 114688;
        int out = i >> 8, k = i & 255;
        float v = fc2W[i];
        int ks = k >> 5, quad = (k >> 3) & 3, e = k & 7, col = out & 15;
        int g = (out >> 4) * 8 + ks;
        F2s[(g * 64 + quad * 16 + col) * 8 + e] = f2bf(v);
    }
}

// x fp32 -> bf16 (packed pairs)
__global__ void convert_x(const float4* __restrict__ x4, uint2* __restrict__ xbf2, int total4) {
    int idx = blockIdx.x * blockDim.x + threadIdx.x;
    if (idx >= total4) return;
    float4 v = x4[idx];
    uint2 o;
    o.x = f2bf2(v.x, v.y);
    o.y = f2bf2(v.z, v.w);
    xbf2[idx] = o;
}

// ---------------- counting sort of edges by dst ----------------

__global__ void hist_kernel(const int* __restrict__ dst, int* __restrict__ degI, int E) {
    int e = blockIdx.x * blockDim.x + threadIdx.x;
    if (e >= E) return;
    atomicAdd(&degI[dst[e]], 1);
}

__global__ void scan_block(const int* __restrict__ degI, int* __restrict__ offs,
                           int* __restrict__ bsum, int N) {
    __shared__ int s[SCAN_B];
    int tid = threadIdx.x;
    int gid = blockIdx.x * SCAN_B + tid;
    int v = (gid < N) ? degI[gid] : 0;
    s[tid] = v;
    __syncthreads();
    for (int off = 1; off < SCAN_B; off <<= 1) {
        int t = (tid >= off) ? s[tid - off] : 0;
        __syncthreads();
        s[tid] += t;
        __syncthreads();
    }
    if (gid < N) offs[gid] = s[tid] - v;
    if (tid == SCAN_B - 1) bsum[blockIdx.x] = s[tid];
}

__global__ void scan_bsum(int* __restrict__ bsum, int nb) {
    __shared__ int s[128];
    int tid = threadIdx.x;
    int v = (tid < nb) ? bsum[tid] : 0;
    s[tid] = v;
    __syncthreads();
    for (int off = 1; off < 128; off <<= 1) {
        int t = (tid >= off) ? s[tid - off] : 0;
        __syncthreads();
        s[tid] += t;
        __syncthreads();
    }
    if (tid < nb) bsum[tid] = s[tid] - v;
}

__global__ void scan_add(int* __restrict__ offs, const int* __restrict__ bsum, int N) {
    int gid = blockIdx.x * SCAN_B + threadIdx.x;
    if (gid < N) offs[gid] += bsum[blockIdx.x];
}

__global__ void reorder_kernel(const int* __restrict__ src, const int* __restrict__ dst,
                               const int* __restrict__ offs, int* __restrict__ cursor,
                               int* __restrict__ srcS, int E) {
    int e = blockIdx.x * blockDim.x + threadIdx.x;
    if (e >= E) return;
    int d = dst[e];
    int pos = offs[d] + atomicAdd(&cursor[d], 1);
    srcS[pos] = src[e];
}

// ---------------- gather: mean of bf16 x rows -> packed bf16 mean ----------------
// one wave per node; lane = uint = 2 features (128 feats total)
__global__ __launch_bounds__(256) void gather_mean_bf(
        const unsigned* __restrict__ xbfu, const int* __restrict__ srcS,
        const int* __restrict__ offs, const int* __restrict__ degI,
        unsigned* __restrict__ meanbf) {
    const int wave = threadIdx.x >> 6, lane = threadIdx.x & 63;
    const int n = blockIdx.x * 4 + wave;
    if (n >= N_NODES) return;
    const int start = offs[n], cnt = degI[n];
    const int* sp = srcS + start;
    float2 a0 = {0.f, 0.f}, a1 = {0.f, 0.f}, a2 = {0.f, 0.f}, a3 = {0.f, 0.f};
    float2 a4 = {0.f, 0.f}, a5 = {0.f, 0.f}, a6 = {0.f, 0.f}, a7 = {0.f, 0.f};
    int j = 0;
    for (; j + 8 <= cnt; j += 8) {
        unsigned v0 = xbfu[sp[j]     * 64 + lane];
        unsigned v1 = xbfu[sp[j + 1] * 64 + lane];
        unsigned v2 = xbfu[sp[j + 2] * 64 + lane];
        unsigned v3 = xbfu[sp[j + 3] * 64 + lane];
        unsigned v4 = xbfu[sp[j + 4] * 64 + lane];
        unsigned v5 = xbfu[sp[j + 5] * 64 + lane];
        unsigned v6 = xbfu[sp[j + 6] * 64 + lane];
        unsigned v7 = xbfu[sp[j + 7] * 64 + lane];
        float2 f0 = bf2f2(v0), f1 = bf2f2(v1), f2 = bf2f2(v2), f3 = bf2f2(v3);
        float2 f4 = bf2f2(v4), f5 = bf2f2(v5), f6 = bf2f2(v6), f7 = bf2f2(v7);
        a0.x += f0.x; a0.y += f0.y;  a1.x += f1.x; a1.y += f1.y;
        a2.x += f2.x; a2.y += f2.y;  a3.x += f3.x; a3.y += f3.y;
        a4.x += f4.x; a4.y += f4.y;  a5.x += f5.x; a5.y += f5.y;
        a6.x += f6.x; a6.y += f6.y;  a7.x += f7.x; a7.y += f7.y;
    }
    for (; j + 2 <= cnt; j += 2) {
        float2 f0 = bf2f2(xbfu[sp[j]     * 64 + lane]);
        float2 f1 = bf2f2(xbfu[sp[j + 1] * 64 + lane]);
        a0.x += f0.x; a0.y += f0.y;
        a1.x += f1.x; a1.y += f1.y;
    }
    if (j < cnt) {
        float2 f0 = bf2f2(xbfu[sp[j] * 64 + lane]);
        a0.x += f0.x; a0.y += f0.y;
    }
    float rd = 1.0f / fmaxf((float)cnt, 1.0f);
    float mx = ((a0.x + a1.x) + (a2.x + a3.x)) + ((a4.x + a5.x) + (a6.x + a7.x));
    float my = ((a0.y + a1.y) + (a2.y + a3.y)) + ((a4.y + a5.y) + (a6.y + a7.y));
    meanbf[n * 64 + lane] = f2bf2(mx * rd, my * rd);
}

// ---------------- layer1 MFMA: [mean|x] -> h -> [z2|r2] ----------------
// ks-outer / nt-inner loops; B-fragments streamed coalesced from swizzled weights.
__global__ __launch_bounds__(256, 4) void layer1_mfma(
        const unsigned* __restrict__ xbfu, const unsigned* __restrict__ meanbf,
        const unsigned short* __restrict__ W1s, const float* __restrict__ bl1,
        const unsigned short* __restrict__ W2s,
        unsigned short* __restrict__ z2bf, float* __restrict__ embOut) {
    __shared__ unsigned short sA[MT][264];
    __shared__ unsigned short sH[MT][264];
    const int tid = threadIdx.x;
    const int node0 = blockIdx.x * MT;

    // staging: 1024 x 16B chunks (mean -> cols 0:128, x -> cols 128:256)
    const uint4* mean4 = (const uint4*)meanbf;
    const uint4* x4    = (const uint4*)xbfu;
#pragma unroll
    for (int it = 0; it < 4; it++) {
        int c = tid + it * 256;
        int row = c >> 5, half = (c >> 4) & 1, ci = c & 15;
        uint4 v = half ? x4[(node0 + row) * 16 + ci]
                       : mean4[(node0 + row) * 16 + ci];
        *(uint4*)&sA[row][half * 128 + ci * 8] = v;
    }
    __syncthreads();

    const int wave = tid >> 6, lane = tid & 63;
    const int col = lane & 15, quad = lane >> 4;

    // ---- phase A: h = relu(A @ W1^T + bl1), N=256, K=256 ----
    floatx4 acc[2][4];
    const floatx4 zero = {0.f, 0.f, 0.f, 0.f};
#pragma unroll
    for (int mt = 0; mt < 2; mt++)
#pragma unroll
        for (int nt = 0; nt < 4; nt++) acc[mt][nt] = zero;

    const short8* w1base = (const short8*)W1s + wave * 2048 + lane;  // wave*4 out-groups * 8 ks * 64
#pragma unroll
    for (int ks = 0; ks < 8; ks++) {
        short8 a0 = *(const short8*)&sA[col][ks * 32 + quad * 8];
        short8 a1 = *(const short8*)&sA[16 + col][ks * 32 + quad * 8];
#pragma unroll
        for (int nt = 0; nt < 4; nt++) {
            short8 b = w1base[(nt * 8 + ks) * 64];
            acc[0][nt] = MFMA16(a0, b, acc[0][nt]);
            acc[1][nt] = MFMA16(a1, b, acc[1][nt]);
        }
    }

#pragma unroll
    for (int nt = 0; nt < 4; nt++) {
        int out = (wave * 4 + nt) * 16 + col;
        float bias = bl1[out];
#pragma unroll
        for (int mt = 0; mt < 2; mt++)
#pragma unroll
            for (int r = 0; r < 4; r++)
                sH[mt * 16 + quad * 4 + r][out] = f2bf(fmaxf(acc[mt][nt][r] + bias, 0.f));
    }
    __syncthreads();

    // ---- phase B: [z2|r2] = h @ W2^T, N=128, K=256 ----
    floatx4 acc2[2][2];
#pragma unroll
    for (int mt = 0; mt < 2; mt++)
#pragma unroll
        for (int nt = 0; nt < 2; nt++) acc2[mt][nt] = zero;

    const short8* w2base = (const short8*)W2s + wave * 1024 + lane;  // wave*2 out-groups * 8 ks * 64
#pragma unroll
    for (int ks = 0; ks < 8; ks++) {
        short8 h0 = *(const short8*)&sH[col][ks * 32 + quad * 8];
        short8 h1 = *(const short8*)&sH[16 + col][ks * 32 + quad * 8];
#pragma unroll
        for (int nt = 0; nt < 2; nt++) {
            short8 b = w2base[(nt * 8 + ks) * 64];
            acc2[0][nt] = MFMA16(h0, b, acc2[0][nt]);
            acc2[1][nt] = MFMA16(h1, b, acc2[1][nt]);
        }
    }

#pragma unroll
    for (int nt = 0; nt < 2; nt++) {
        int out = (wave * 2 + nt) * 16 + col;
#pragma unroll
        for (int mt = 0; mt < 2; mt++)
#pragma unroll
            for (int r = 0; r < 4; r++) {
                int node = node0 + mt * 16 + quad * 4 + r;
                float v = acc2[mt][nt][r];
                if (out < 64) z2bf[node * 64 + out] = f2bf(v);
                else          embOut[node * 64 + (out - 64)] = v;
            }
    }
}

// ---------------- gather: emb = agg(z2)/deg + bl2 + r2 ----------------
__global__ __launch_bounds__(256) void gather_emb(
        const unsigned* __restrict__ z2u, const int* __restrict__ srcS,
        const int* __restrict__ offs, const int* __restrict__ degI,
        const float* __restrict__ bl2, float* __restrict__ emb,
        unsigned* __restrict__ embbf) {
    const int wave = threadIdx.x >> 6, lane = threadIdx.x & 63;
    const int n = blockIdx.x * 4 + wave;
    if (n >= N_NODES) return;
    const int start = offs[n], cnt = degI[n];
    const int* sp = srcS + start;
    const int half = lane >> 5, l32 = lane & 31;
    float a0x = 0.f, a0y = 0.f, a1x = 0.f, a1y = 0.f;
    float a2x = 0.f, a2y = 0.f, a3x = 0.f, a3y = 0.f;
    int j = 0;
    for (; j + 8 <= cnt; j += 8) {
        unsigned v0 = z2u[sp[j + half]     * 32 + l32];
        unsigned v1 = z2u[sp[j + 2 + half] * 32 + l32];
        unsigned v2 = z2u[sp[j + 4 + half] * 32 + l32];
        unsigned v3 = z2u[sp[j + 6 + half] * 32 + l32];
        float2 f0 = bf2f2(v0), f1 = bf2f2(v1), f2 = bf2f2(v2), f3 = bf2f2(v3);
        a0x += f0.x; a0y += f0.y;  a1x += f1.x; a1y += f1.y;
        a2x += f2.x; a2y += f2.y;  a3x += f3.x; a3y += f3.y;
    }
    for (; j + 2 <= cnt; j += 2) {
        float2 f0 = bf2f2(z2u[sp[j + half] * 32 + l32]);
        a0x += f0.x; a0y += f0.y;
    }
    if ((cnt & 1) && half == 0) {
        float2 f0 = bf2f2(z2u[sp[cnt - 1] * 32 + l32]);
        a0x += f0.x; a0y += f0.y;
    }
    float ax = (a0x + a1x) + (a2x + a3x);
    float ay = (a0y + a1y) + (a2y + a3y);
    ax += __shfl_down(ax, 32);
    ay += __shfl_down(ay, 32);
    if (half == 0) {
        float rd = 1.0f / fmaxf((float)cnt, 1.0f);
        float2 r2v = *(const float2*)&emb[n * 64 + l32 * 2];
        float ex = ax * rd + bl2[l32 * 2]     + r2v.x;
        float ey = ay * rd + bl2[l32 * 2 + 1] + r2v.y;
        float2 ev = {ex, ey};
        *(float2*)&emb[n * 64 + l32 * 2] = ev;
        embbf[n * 32 + l32] = f2bf2(ex, ey);
    }
}

// ---------------- decoder MFMA: emb -> hid -> recon ----------------
__global__ __launch_bounds__(256, 4) void decoder_mfma(
        const unsigned* __restrict__ embbf,
        const unsigned short* __restrict__ F1s, const float* __restrict__ fc1b,
        const unsigned short* __restrict__ F2s, const float* __restrict__ fc2b,
        float* __restrict__ recon) {
    __shared__ unsigned short sE[MT][72];
    __shared__ unsigned short sH[MT][264];
    const int tid = threadIdx.x;
    const int node0 = blockIdx.x * MT;

    // staging: 256 x 16B chunks, 1 per thread
    {
        const uint4* e4 = (const uint4*)embbf;
        int row = tid >> 3, ci = tid & 7;
        *(uint4*)&sE[row][ci * 8] = e4[(node0 + row) * 8 + ci];
    }
    __syncthreads();

    const int wave = tid >> 6, lane = tid & 63;
    const int col = lane & 15, quad = lane >> 4;

    // ---- phase A: hid = relu(emb @ fc1^T + fc1b), N=256, K=64 ----
    floatx4 acc[2][4];
    const floatx4 zero = {0.f, 0.f, 0.f, 0.f};
#pragma unroll
    for (int mt = 0; mt < 2; mt++)
#pragma unroll
        for (int nt = 0; nt < 4; nt++) acc[mt][nt] = zero;

    const short8* f1base = (const short8*)F1s + wave * 512 + lane;  // wave*4 out-groups * 2 ks * 64
#pragma unroll
    for (int ks = 0; ks < 2; ks++) {
        short8 a0 = *(const short8*)&sE[col][ks * 32 + quad * 8];
        short8 a1 = *(const short8*)&sE[16 + col][ks * 32 + quad * 8];
#pragma unroll
        for (int nt = 0; nt < 4; nt++) {
            short8 b = f1base[(nt * 2 + ks) * 64];
            acc[0][nt] = MFMA16(a0, b, acc[0][nt]);
            acc[1][nt] = MFMA16(a1, b, acc[1][nt]);
        }
    }

#pragma unroll
    for (int nt = 0; nt < 4; nt++) {
        int out = (wave * 4 + nt) * 16 + col;
        float bias = fc1b[out];
#pragma unroll
        for (int mt = 0; mt < 2; mt++)
#pragma unroll
            for (int r = 0; r < 4; r++)
                sH[mt * 16 + quad * 4 + r][out] = f2bf(fmaxf(acc[mt][nt][r] + bias, 0.f));
    }
    __syncthreads();

    // ---- phase B: recon = hid @ fc2^T + fc2b, N=128, K=256 ----
    floatx4 acc2[2][2];
#pragma unroll
    for (int mt = 0; mt < 2; mt++)
#pragma unroll
        for (int nt = 0; nt < 2; nt++) acc2[mt][nt] = zero;

    const short8* f2base = (const short8*)F2s + wave * 1024 + lane;  // wave*2 out-groups * 8 ks * 64
#pragma unroll
    for (int ks = 0; ks < 8; ks++) {
        short8 h0 = *(const short8*)&sH[col][ks * 32 + quad * 8];
        short8 h1 = *(const short8*)&sH[16 + col][ks * 32 + quad * 8];
#pragma unroll
        for (int nt = 0; nt < 2; nt++) {
            short8 b = f2base[(nt * 8 + ks) * 64];
            acc2[0][nt] = MFMA16(h0, b, acc2[0][nt]);
            acc2[1][nt] = MFMA16(h1, b, acc2[1][nt]);
        }
    }

#pragma unroll
    for (int nt = 0; nt < 2; nt++) {
        int out = (wave * 2 + nt) * 16 + col;
        float bias = fc2b[out];
#pragma unroll
        for (int mt = 0; mt < 2; mt++)
#pragma unroll
            for (int r = 0; r < 4; r++) {
                int node = node0 + mt * 16 + quad * 4 + r;
                recon[node * 128 + out] = acc2[mt][nt][r] + bias;
            }
    }
}

extern "C" void kernel_launch(void* const* d_in, const int* in_sizes, int n_in,
                              void* d_out, int out_size, void* d_ws, size_t ws_size,
                              hipStream_t stream) {
    const float* x    = (const float*)d_in[0];
    const int*   ei   = (const int*)d_in[1];
    const int E = in_sizes[1] / 2;
    const int* src = ei;
    const int* dst = ei + E;
    const float* Wl1  = (const float*)d_in[2];
    const float* bl1  = (const float*)d_in[3];
    const float* Wr1  = (const float*)d_in[4];
    const float* Wl2  = (const float*)d_in[5];
    const float* bl2  = (const float*)d_in[6];
    const float* Wr2  = (const float*)d_in[7];
    const float* fc1W = (const float*)d_in[8];
    const float* fc1b = (const float*)d_in[9];
    const float* fc2W = (const float*)d_in[10];
    const float* fc2b = (const float*)d_in[11];

    float* out   = (float*)d_out;
    float* emb   = out;                           // N*64
    float* recon = out + (size_t)N_NODES * D_E;   // N*128

    // workspace layout (512-aligned offsets)
    char* ws = (char*)d_ws;
    unsigned short* xbf    = (unsigned short*)(ws);             // 25,600,000 B
    unsigned*       meanbf = (unsigned*)(ws + 25600000);        // 25,600,000 B
    unsigned short* z2bf   = (unsigned short*)(ws + 51200000);  // 12,800,000 B
    unsigned*       embbf  = (unsigned*)(ws + 64000000);        // 12,800,000 B
    int* degI   = (int*)(ws + 76800000);                        //    400,000 B
    int* offs   = (int*)(ws + 77200384);                        //    400,000 B
    int* cursor = (int*)(ws + 77600768);                        //    400,000 B
    int* bsum   = (int*)(ws + 78001152);                        //        512 B
    int* srcS   = (int*)(ws + 78001664);                        //  6,400,000 B
    unsigned short* W1s = (unsigned short*)(ws + 84401664);     //    131,072 B
    unsigned short* W2s = (unsigned short*)(ws + 84532736);     //     65,536 B
    unsigned short* F1s = (unsigned short*)(ws + 84598272);     //     32,768 B
    unsigned short* F2s = (unsigned short*)(ws + 84631040);     //     65,536 B
    // end 84,696,576 B

    hipMemsetAsync(degI,   0, (size_t)N_NODES * sizeof(int), stream);
    hipMemsetAsync(cursor, 0, (size_t)N_NODES * sizeof(int), stream);

    convert_weights<<<(147456 + 255) / 256, 256, 0, stream>>>(
        Wl1, Wr1, Wl2, Wr2, fc1W, fc2W, W1s, W2s, F1s, F2s);
    convert_x<<<(N_NODES * 32 + 255) / 256, 256, 0, stream>>>(
        (const float4*)x, (uint2*)xbf, N_NODES * 32);

    // counting sort of edges by dst
    hist_kernel<<<(E + 255) / 256, 256, 0, stream>>>(dst, degI, E);
    const int nScanBlocks = (N_NODES + SCAN_B - 1) / SCAN_B;  // 98
    scan_block<<<nScanBlocks, SCAN_B, 0, stream>>>(degI, offs, bsum, N_NODES);
    scan_bsum<<<1, 128, 0, stream>>>(bsum, nScanBlocks);
    scan_add<<<nScanBlocks, SCAN_B, 0, stream>>>(offs, bsum, N_NODES);
    reorder_kernel<<<(E + 255) / 256, 256, 0, stream>>>(src, dst, offs, cursor, srcS, E);

    // layer 1
    gather_mean_bf<<<(N_NODES + 3) / 4, 256, 0, stream>>>(
        (const unsigned*)xbf, srcS, offs, degI, meanbf);
    layer1_mfma<<<N_NODES / MT, 256, 0, stream>>>(
        (const unsigned*)xbf, meanbf, W1s, bl1, W2s, z2bf, emb);

    // layer 2 aggregation + emb finalize
    gather_emb<<<(N_NODES + 3) / 4, 256, 0, stream>>>(
        (const unsigned*)z2bf, srcS, offs, degI, bl2, emb, embbf);

    // decoder
    decoder_mfma<<<N_NODES / MT, 256, 0, stream>>>(
        embbf, F1s, fc1b, F2s, fc2b, recon);
}

// Round 2
// 450.871 us; speedup vs baseline: 1.1881x; 1.0185x over previous
//
#include <hip/hip_runtime.h>
#include <hip/hip_bf16.h>

#define N_NODES 100000
#define D_IN 128
#define D_H 256
#define D_E 64
#define MT 32        // nodes per GEMM block
#define SCAN_B 1024  // scan block size

typedef __attribute__((ext_vector_type(8))) short short8;
typedef __attribute__((ext_vector_type(4))) float floatx4;

__device__ inline unsigned short f2bf(float f) {
    union { float f; unsigned u; } v; v.f = f;
    unsigned r = v.u + 0x7FFF + ((v.u >> 16) & 1);
    return (unsigned short)(r >> 16);
}
__device__ inline unsigned f2bf2(float a, float b) {
    return (unsigned)f2bf(a) | ((unsigned)f2bf(b) << 16);
}
__device__ inline float2 bf2f2(unsigned v) {
    union { unsigned u; float f; } lo, hi;
    lo.u = v << 16;
    hi.u = v & 0xffff0000u;
    return make_float2(lo.f, hi.f);  // .x = lower-address bf16
}

#define MFMA16(a, b, c) __builtin_amdgcn_mfma_f32_16x16x32_bf16((a), (b), (c), 0, 0, 0)

// ---------------- weight pre-pack to bf16, SWIZZLED to MFMA fragment order ----
// B-fragment for (out-group g16=out>>4, ks, lane{quad,col}) is stored contiguously:
//   chunk_index = (g16*KS + ks)*64 + quad*16 + col   (chunk = 8 shorts = 16B)
//   element e of chunk = W[out = g16*16+col][k = ks*32 + quad*8 + e]
// -> every wave B-load is a fully coalesced 1KB global_load_dwordx4.
__global__ void convert_weights(const float* __restrict__ Wl1, const float* __restrict__ Wr1,
                                const float* __restrict__ Wl2, const float* __restrict__ Wr2,
                                const float* __restrict__ fc1W, const float* __restrict__ fc2W,
                                unsigned short* __restrict__ W1s, unsigned short* __restrict__ W2s,
                                unsigned short* __restrict__ F1s, unsigned short* __restrict__ F2s) {
    int idx = blockIdx.x * blockDim.x + threadIdx.x;
    if (idx < 65536) {
        // W1: 256 outs x 256 k of [Wl1 | Wr1]
        int out = idx >> 8, k = idx & 255;
        float v = (k < 128) ? Wl1[out * 128 + k] : Wr1[out * 128 + (k - 128)];
        int ks = k >> 5, quad = (k >> 3) & 3, e = k & 7, col = out & 15;
        int g = (out >> 4) * 8 + ks;
        W1s[(g * 64 + quad * 16 + col) * 8 + e] = f2bf(v);
    } else if (idx < 98304) {
        // W2: 128 outs x 256 k of [Wl2 ; Wr2]
        int i = idx - 65536; int out = i >> 8, k = i & 255;
        float v = (out < 64) ? Wl2[out * 256 + k] : Wr2[(out - 64) * 256 + k];
        int ks = k >> 5, quad = (k >> 3) & 3, e = k & 7, col = out & 15;
        int g = (out >> 4) * 8 + ks;
        W2s[(g * 64 + quad * 16 + col) * 8 + e] = f2bf(v);
    } else if (idx < 114688) {
        // fc1: 256 outs x 64 k
        int i = idx - 98304;
        int out = i >> 6, k = i & 63;
        float v = fc1W[i];
        int ks = k >> 5, quad = (k >> 3) & 3, e = k & 7, col = out & 15;
        int g = (out >> 4) * 2 + ks;
        F1s[(g * 64 + quad * 16 + col) * 8 + e] = f2bf(v);
    } else if (idx < 147456) {
        // fc2: 128 outs x 256 k
        int i = idx - 114688;
        int out = i >> 8, k = i & 255;
        float v = fc2W[i];
        int ks = k >> 5, quad = (k >> 3) & 3, e = k & 7, col = out & 15;
        int g = (out >> 4) * 8 + ks;
        F2s[(g * 64 + quad * 16 + col) * 8 + e] = f2bf(v);
    }
}

// x fp32 -> bf16 (packed pairs)
__global__ void convert_x(const float4* __restrict__ x4, uint2* __restrict__ xbf2, int total4) {
    int idx = blockIdx.x * blockDim.x + threadIdx.x;
    if (idx >= total4) return;
    float4 v = x4[idx];
    uint2 o;
    o.x = f2bf2(v.x, v.y);
    o.y = f2bf2(v.z, v.w);
    xbf2[idx] = o;
}

// ---------------- counting sort of edges by dst ----------------

__global__ void hist_kernel(const int* __restrict__ dst, int* __restrict__ degI, int E) {
    int e = blockIdx.x * blockDim.x + threadIdx.x;
    if (e >= E) return;
    atomicAdd(&degI[dst[e]], 1);
}

__global__ void scan_block(const int* __restrict__ degI, int* __restrict__ offs,
                           int* __restrict__ bsum, int N) {
    __shared__ int s[SCAN_B];
    int tid = threadIdx.x;
    int gid = blockIdx.x * SCAN_B + tid;
    int v = (gid < N) ? degI[gid] : 0;
    s[tid] = v;
    __syncthreads();
    for (int off = 1; off < SCAN_B; off <<= 1) {
        int t = (tid >= off) ? s[tid - off] : 0;
        __syncthreads();
        s[tid] += t;
        __syncthreads();
    }
    if (gid < N) offs[gid] = s[tid] - v;
    if (tid == SCAN_B - 1) bsum[blockIdx.x] = s[tid];
}

__global__ void scan_bsum(int* __restrict__ bsum, int nb) {
    __shared__ int s[128];
    int tid = threadIdx.x;
    int v = (tid < nb) ? bsum[tid] : 0;
    s[tid] = v;
    __syncthreads();
    for (int off = 1; off < 128; off <<= 1) {
        int t = (tid >= off) ? s[tid - off] : 0;
        __syncthreads();
        s[tid] += t;
        __syncthreads();
    }
    if (tid < nb) bsum[tid] = s[tid] - v;
}

__global__ void scan_add(int* __restrict__ offs, const int* __restrict__ bsum, int N) {
    int gid = blockIdx.x * SCAN_B + threadIdx.x;
    if (gid < N) offs[gid] += bsum[blockIdx.x];
}

// dst-range x XCD partitioned scatter: block handles range (blockIdx & 7) over
// edge-slice (blockIdx >> 3). All writes to one 800KB srcS range come from one
// XCD (blockIdx%8 -> XCD round-robin heuristic) -> lines fill in that XCD's L2
// before eviction -> write amplification collapses. dst/src re-reads (8x) are
// L3-resident after the first range group.
#define REORDER_SLICES 512
__global__ __launch_bounds__(256) void reorder_kernel(
        const int* __restrict__ src, const int* __restrict__ dst,
        const int* __restrict__ offs, int* __restrict__ cursor,
        int* __restrict__ srcS, int E) {
    const int range = blockIdx.x & 7;
    const int slice = blockIdx.x >> 3;
    const int lo = range * 12500, hi = lo + 12500;
    const int stride = REORDER_SLICES * 256;
    for (int e = slice * 256 + threadIdx.x; e < E; e += stride) {
        int d = dst[e];
        if (d < lo || d >= hi) continue;
        int pos = offs[d] + atomicAdd(&cursor[d], 1);
        srcS[pos] = src[e];
    }
}

// ---------------- gather: mean of bf16 x rows -> packed bf16 mean ----------------
// one wave per node; lane = uint = 2 features (128 feats total)
__global__ __launch_bounds__(256) void gather_mean_bf(
        const unsigned* __restrict__ xbfu, const int* __restrict__ srcS,
        const int* __restrict__ offs, const int* __restrict__ degI,
        unsigned* __restrict__ meanbf) {
    const int wave = threadIdx.x >> 6, lane = threadIdx.x & 63;
    const int n = blockIdx.x * 4 + wave;
    if (n >= N_NODES) return;
    const int start = offs[n], cnt = degI[n];
    const int* sp = srcS + start;
    float2 a0 = {0.f, 0.f}, a1 = {0.f, 0.f}, a2 = {0.f, 0.f}, a3 = {0.f, 0.f};
    float2 a4 = {0.f, 0.f}, a5 = {0.f, 0.f}, a6 = {0.f, 0.f}, a7 = {0.f, 0.f};
    int j = 0;
    for (; j + 8 <= cnt; j += 8) {
        unsigned v0 = xbfu[sp[j]     * 64 + lane];
        unsigned v1 = xbfu[sp[j + 1] * 64 + lane];
        unsigned v2 = xbfu[sp[j + 2] * 64 + lane];
        unsigned v3 = xbfu[sp[j + 3] * 64 + lane];
        unsigned v4 = xbfu[sp[j + 4] * 64 + lane];
        unsigned v5 = xbfu[sp[j + 5] * 64 + lane];
        unsigned v6 = xbfu[sp[j + 6] * 64 + lane];
        unsigned v7 = xbfu[sp[j + 7] * 64 + lane];
        float2 f0 = bf2f2(v0), f1 = bf2f2(v1), f2 = bf2f2(v2), f3 = bf2f2(v3);
        float2 f4 = bf2f2(v4), f5 = bf2f2(v5), f6 = bf2f2(v6), f7 = bf2f2(v7);
        a0.x += f0.x; a0.y += f0.y;  a1.x += f1.x; a1.y += f1.y;
        a2.x += f2.x; a2.y += f2.y;  a3.x += f3.x; a3.y += f3.y;
        a4.x += f4.x; a4.y += f4.y;  a5.x += f5.x; a5.y += f5.y;
        a6.x += f6.x; a6.y += f6.y;  a7.x += f7.x; a7.y += f7.y;
    }
    for (; j + 2 <= cnt; j += 2) {
        float2 f0 = bf2f2(xbfu[sp[j]     * 64 + lane]);
        float2 f1 = bf2f2(xbfu[sp[j + 1] * 64 + lane]);
        a0.x += f0.x; a0.y += f0.y;
        a1.x += f1.x; a1.y += f1.y;
    }
    if (j < cnt) {
        float2 f0 = bf2f2(xbfu[sp[j] * 64 + lane]);
        a0.x += f0.x; a0.y += f0.y;
    }
    float rd = 1.0f / fmaxf((float)cnt, 1.0f);
    float mx = ((a0.x + a1.x) + (a2.x + a3.x)) + ((a4.x + a5.x) + (a6.x + a7.x));
    float my = ((a0.y + a1.y) + (a2.y + a3.y)) + ((a4.y + a5.y) + (a6.y + a7.y));
    meanbf[n * 64 + lane] = f2bf2(mx * rd, my * rd);
}

// ---------------- layer1 MFMA: [mean|x] -> h -> [z2|r2] ----------------
// ks-outer / nt-inner loops; B-fragments streamed coalesced from swizzled weights.
__global__ __launch_bounds__(256, 4) void layer1_mfma(
        const unsigned* __restrict__ xbfu, const unsigned* __restrict__ meanbf,
        const unsigned short* __restrict__ W1s, const float* __restrict__ bl1,
        const unsigned short* __restrict__ W2s,
        unsigned short* __restrict__ z2bf, float* __restrict__ embOut) {
    __shared__ unsigned short sA[MT][264];
    __shared__ unsigned short sH[MT][264];
    const int tid = threadIdx.x;
    const int node0 = blockIdx.x * MT;

    // staging: 1024 x 16B chunks (mean -> cols 0:128, x -> cols 128:256)
    const uint4* mean4 = (const uint4*)meanbf;
    const uint4* x4    = (const uint4*)xbfu;
#pragma unroll
    for (int it = 0; it < 4; it++) {
        int c = tid + it * 256;
        int row = c >> 5, half = (c >> 4) & 1, ci = c & 15;
        uint4 v = half ? x4[(node0 + row) * 16 + ci]
                       : mean4[(node0 + row) * 16 + ci];
        *(uint4*)&sA[row][half * 128 + ci * 8] = v;
    }
    __syncthreads();

    const int wave = tid >> 6, lane = tid & 63;
    const int col = lane & 15, quad = lane >> 4;

    // ---- phase A: h = relu(A @ W1^T + bl1), N=256, K=256 ----
    floatx4 acc[2][4];
    const floatx4 zero = {0.f, 0.f, 0.f, 0.f};
#pragma unroll
    for (int mt = 0; mt < 2; mt++)
#pragma unroll
        for (int nt = 0; nt < 4; nt++) acc[mt][nt] = zero;

    const short8* w1base = (const short8*)W1s + wave * 2048 + lane;  // wave*4 out-groups * 8 ks * 64
#pragma unroll
    for (int ks = 0; ks < 8; ks++) {
        short8 a0 = *(const short8*)&sA[col][ks * 32 + quad * 8];
        short8 a1 = *(const short8*)&sA[16 + col][ks * 32 + quad * 8];
#pragma unroll
        for (int nt = 0; nt < 4; nt++) {
            short8 b = w1base[(nt * 8 + ks) * 64];
            acc[0][nt] = MFMA16(a0, b, acc[0][nt]);
            acc[1][nt] = MFMA16(a1, b, acc[1][nt]);
        }
    }

#pragma unroll
    for (int nt = 0; nt < 4; nt++) {
        int out = (wave * 4 + nt) * 16 + col;
        float bias = bl1[out];
#pragma unroll
        for (int mt = 0; mt < 2; mt++)
#pragma unroll
            for (int r = 0; r < 4; r++)
                sH[mt * 16 + quad * 4 + r][out] = f2bf(fmaxf(acc[mt][nt][r] + bias, 0.f));
    }
    __syncthreads();

    // ---- phase B: [z2|r2] = h @ W2^T, N=128, K=256 ----
    floatx4 acc2[2][2];
#pragma unroll
    for (int mt = 0; mt < 2; mt++)
#pragma unroll
        for (int nt = 0; nt < 2; nt++) acc2[mt][nt] = zero;

    const short8* w2base = (const short8*)W2s + wave * 1024 + lane;  // wave*2 out-groups * 8 ks * 64
#pragma unroll
    for (int ks = 0; ks < 8; ks++) {
        short8 h0 = *(const short8*)&sH[col][ks * 32 + quad * 8];
        short8 h1 = *(const short8*)&sH[16 + col][ks * 32 + quad * 8];
#pragma unroll
        for (int nt = 0; nt < 2; nt++) {
            short8 b = w2base[(nt * 8 + ks) * 64];
            acc2[0][nt] = MFMA16(h0, b, acc2[0][nt]);
            acc2[1][nt] = MFMA16(h1, b, acc2[1][nt]);
        }
    }

#pragma unroll
    for (int nt = 0; nt < 2; nt++) {
        int out = (wave * 2 + nt) * 16 + col;
#pragma unroll
        for (int mt = 0; mt < 2; mt++)
#pragma unroll
            for (int r = 0; r < 4; r++) {
                int node = node0 + mt * 16 + quad * 4 + r;
                float v = acc2[mt][nt][r];
                if (out < 64) z2bf[node * 64 + out] = f2bf(v);
                else          embOut[node * 64 + (out - 64)] = v;
            }
    }
}

// ---------------- gather: emb = agg(z2)/deg + bl2 + r2 ----------------
__global__ __launch_bounds__(256) void gather_emb(
        const unsigned* __restrict__ z2u, const int* __restrict__ srcS,
        const int* __restrict__ offs, const int* __restrict__ degI,
        const float* __restrict__ bl2, float* __restrict__ emb,
        unsigned* __restrict__ embbf) {
    const int wave = threadIdx.x >> 6, lane = threadIdx.x & 63;
    const int n = blockIdx.x * 4 + wave;
    if (n >= N_NODES) return;
    const int start = offs[n], cnt = degI[n];
    const int* sp = srcS + start;
    const int half = lane >> 5, l32 = lane & 31;
    float a0x = 0.f, a0y = 0.f, a1x = 0.f, a1y = 0.f;
    float a2x = 0.f, a2y = 0.f, a3x = 0.f, a3y = 0.f;
    int j = 0;
    for (; j + 8 <= cnt; j += 8) {
        unsigned v0 = z2u[sp[j + half]     * 32 + l32];
        unsigned v1 = z2u[sp[j + 2 + half] * 32 + l32];
        unsigned v2 = z2u[sp[j + 4 + half] * 32 + l32];
        unsigned v3 = z2u[sp[j + 6 + half] * 32 + l32];
        float2 f0 = bf2f2(v0), f1 = bf2f2(v1), f2 = bf2f2(v2), f3 = bf2f2(v3);
        a0x += f0.x; a0y += f0.y;  a1x += f1.x; a1y += f1.y;
        a2x += f2.x; a2y += f2.y;  a3x += f3.x; a3y += f3.y;
    }
    for (; j + 2 <= cnt; j += 2) {
        float2 f0 = bf2f2(z2u[sp[j + half] * 32 + l32]);
        a0x += f0.x; a0y += f0.y;
    }
    if ((cnt & 1) && half == 0) {
        float2 f0 = bf2f2(z2u[sp[cnt - 1] * 32 + l32]);
        a0x += f0.x; a0y += f0.y;
    }
    float ax = (a0x + a1x) + (a2x + a3x);
    float ay = (a0y + a1y) + (a2y + a3y);
    ax += __shfl_down(ax, 32);
    ay += __shfl_down(ay, 32);
    if (half == 0) {
        float rd = 1.0f / fmaxf((float)cnt, 1.0f);
        float2 r2v = *(const float2*)&emb[n * 64 + l32 * 2];
        float ex = ax * rd + bl2[l32 * 2]     + r2v.x;
        float ey = ay * rd + bl2[l32 * 2 + 1] + r2v.y;
        float2 ev = {ex, ey};
        *(float2*)&emb[n * 64 + l32 * 2] = ev;
        embbf[n * 32 + l32] = f2bf2(ex, ey);
    }
}

// ---------------- decoder MFMA: emb -> hid -> recon ----------------
__global__ __launch_bounds__(256, 4) void decoder_mfma(
        const unsigned* __restrict__ embbf,
        const unsigned short* __restrict__ F1s, const float* __restrict__ fc1b,
        const unsigned short* __restrict__ F2s, const float* __restrict__ fc2b,
        float* __restrict__ recon) {
    __shared__ unsigned short sE[MT][72];
    __shared__ unsigned short sH[MT][264];
    const int tid = threadIdx.x;
    const int node0 = blockIdx.x * MT;

    // staging: 256 x 16B chunks, 1 per thread
    {
        const uint4* e4 = (const uint4*)embbf;
        int row = tid >> 3, ci = tid & 7;
        *(uint4*)&sE[row][ci * 8] = e4[(node0 + row) * 8 + ci];
    }
    __syncthreads();

    const int wave = tid >> 6, lane = tid & 63;
    const int col = lane & 15, quad = lane >> 4;

    // ---- phase A: hid = relu(emb @ fc1^T + fc1b), N=256, K=64 ----
    floatx4 acc[2][4];
    const floatx4 zero = {0.f, 0.f, 0.f, 0.f};
#pragma unroll
    for (int mt = 0; mt < 2; mt++)
#pragma unroll
        for (int nt = 0; nt < 4; nt++) acc[mt][nt] = zero;

    const short8* f1base = (const short8*)F1s + wave * 512 + lane;  // wave*4 out-groups * 2 ks * 64
#pragma unroll
    for (int ks = 0; ks < 2; ks++) {
        short8 a0 = *(const short8*)&sE[col][ks * 32 + quad * 8];
        short8 a1 = *(const short8*)&sE[16 + col][ks * 32 + quad * 8];
#pragma unroll
        for (int nt = 0; nt < 4; nt++) {
            short8 b = f1base[(nt * 2 + ks) * 64];
            acc[0][nt] = MFMA16(a0, b, acc[0][nt]);
            acc[1][nt] = MFMA16(a1, b, acc[1][nt]);
        }
    }

#pragma unroll
    for (int nt = 0; nt < 4; nt++) {
        int out = (wave * 4 + nt) * 16 + col;
        float bias = fc1b[out];
#pragma unroll
        for (int mt = 0; mt < 2; mt++)
#pragma unroll
            for (int r = 0; r < 4; r++)
                sH[mt * 16 + quad * 4 + r][out] = f2bf(fmaxf(acc[mt][nt][r] + bias, 0.f));
    }
    __syncthreads();

    // ---- phase B: recon = hid @ fc2^T + fc2b, N=128, K=256 ----
    floatx4 acc2[2][2];
#pragma unroll
    for (int mt = 0; mt < 2; mt++)
#pragma unroll
        for (int nt = 0; nt < 2; nt++) acc2[mt][nt] = zero;

    const short8* f2base = (const short8*)F2s + wave * 1024 + lane;  // wave*2 out-groups * 8 ks * 64
#pragma unroll
    for (int ks = 0; ks < 8; ks++) {
        short8 h0 = *(const short8*)&sH[col][ks * 32 + quad * 8];
        short8 h1 = *(const short8*)&sH[16 + col][ks * 32 + quad * 8];
#pragma unroll
        for (int nt = 0; nt < 2; nt++) {
            short8 b = f2base[(nt * 8 + ks) * 64];
            acc2[0][nt] = MFMA16(h0, b, acc2[0][nt]);
            acc2[1][nt] = MFMA16(h1, b, acc2[1][nt]);
        }
    }

#pragma unroll
    for (int nt = 0; nt < 2; nt++) {
        int out = (wave * 2 + nt) * 16 + col;
        float bias = fc2b[out];
#pragma unroll
        for (int mt = 0; mt < 2; mt++)
#pragma unroll
            for (int r = 0; r < 4; r++) {
                int node = node0 + mt * 16 + quad * 4 + r;
                recon[node * 128 + out] = acc2[mt][nt][r] + bias;
            }
    }
}

extern "C" void kernel_launch(void* const* d_in, const int* in_sizes, int n_in,
                              void* d_out, int out_size, void* d_ws, size_t ws_size,
                              hipStream_t stream) {
    const float* x    = (const float*)d_in[0];
    const int*   ei   = (const int*)d_in[1];
    const int E = in_sizes[1] / 2;
    const int* src = ei;
    const int* dst = ei + E;
    const float* Wl1  = (const float*)d_in[2];
    const float* bl1  = (const float*)d_in[3];
    const float* Wr1  = (const float*)d_in[4];
    const float* Wl2  = (const float*)d_in[5];
    const float* bl2  = (const float*)d_in[6];
    const float* Wr2  = (const float*)d_in[7];
    const float* fc1W = (const float*)d_in[8];
    const float* fc1b = (const float*)d_in[9];
    const float* fc2W = (const float*)d_in[10];
    const float* fc2b = (const float*)d_in[11];

    float* out   = (float*)d_out;
    float* emb   = out;                           // N*64
    float* recon = out + (size_t)N_NODES * D_E;   // N*128

    // workspace layout (512-aligned offsets)
    char* ws = (char*)d_ws;
    unsigned short* xbf    = (unsigned short*)(ws);             // 25,600,000 B
    unsigned*       meanbf = (unsigned*)(ws + 25600000);        // 25,600,000 B
    unsigned short* z2bf   = (unsigned short*)(ws + 51200000);  // 12,800,000 B
    unsigned*       embbf  = (unsigned*)(ws + 64000000);        // 12,800,000 B
    int* degI   = (int*)(ws + 76800000);                        //    400,000 B
    int* offs   = (int*)(ws + 77200384);                        //    400,000 B
    int* cursor = (int*)(ws + 77600768);                        //    400,000 B
    int* bsum   = (int*)(ws + 78001152);                        //        512 B
    int* srcS   = (int*)(ws + 78001664);                        //  6,400,000 B
    unsigned short* W1s = (unsigned short*)(ws + 84401664);     //    131,072 B
    unsigned short* W2s = (unsigned short*)(ws + 84532736);     //     65,536 B
    unsigned short* F1s = (unsigned short*)(ws + 84598272);     //     32,768 B
    unsigned short* F2s = (unsigned short*)(ws + 84631040);     //     65,536 B
    // end 84,696,576 B

    hipMemsetAsync(degI,   0, (size_t)N_NODES * sizeof(int), stream);
    hipMemsetAsync(cursor, 0, (size_t)N_NODES * sizeof(int), stream);

    convert_weights<<<(147456 + 255) / 256, 256, 0, stream>>>(
        Wl1, Wr1, Wl2, Wr2, fc1W, fc2W, W1s, W2s, F1s, F2s);
    convert_x<<<(N_NODES * 32 + 255) / 256, 256, 0, stream>>>(
        (const float4*)x, (uint2*)xbf, N_NODES * 32);

    // counting sort of edges by dst
    hist_kernel<<<(E + 255) / 256, 256, 0, stream>>>(dst, degI, E);
    const int nScanBlocks = (N_NODES + SCAN_B - 1) / SCAN_B;  // 98
    scan_block<<<nScanBlocks, SCAN_B, 0, stream>>>(degI, offs, bsum, N_NODES);
    scan_bsum<<<1, 128, 0, stream>>>(bsum, nScanBlocks);
    scan_add<<<nScanBlocks, SCAN_B, 0, stream>>>(offs, bsum, N_NODES);
    reorder_kernel<<<8 * REORDER_SLICES, 256, 0, stream>>>(src, dst, offs, cursor, srcS, E);

    // layer 1
    gather_mean_bf<<<(N_NODES + 3) / 4, 256, 0, stream>>>(
        (const unsigned*)xbf, srcS, offs, degI, meanbf);
    layer1_mfma<<<N_NODES / MT, 256, 0, stream>>>(
        (const unsigned*)xbf, meanbf, W1s, bl1, W2s, z2bf, emb);

    // layer 2 aggregation + emb finalize
    gather_emb<<<(N_NODES + 3) / 4, 256, 0, stream>>>(
        (const unsigned*)z2bf, srcS, offs, degI, bl2, emb, embbf);

    // decoder
    decoder_mfma<<<N_NODES / MT, 256, 0, stream>>>(
        embbf, F1s, fc1b, F2s, fc2b, recon);
}